// Round 1
// baseline (683.560 us; speedup 1.0000x reference)
//
#include <hip/hip_runtime.h>
#include <math.h>

#define NB 8
#define NTOK 2048
#define DD 64
#define HH 256
#define NROWS (NB * NTOK)   // 16384

// ---------------------------------------------------------------------------
// Fused 3-layer MLP:  Y[rows,64] = relu(relu(X@W1+b1)@W2+b2)@W3+b3
// 32-row tile per block, 256 threads. Activations in LDS (broadcast reads),
// weights streamed from global (L2-resident: 384 KB total).
// ---------------------------------------------------------------------------
__global__ __launch_bounds__(256, 2) void mlp_kernel(
    const float* __restrict__ X, float* __restrict__ Y,
    const float* __restrict__ W1, const float* __restrict__ b1,
    const float* __restrict__ W2, const float* __restrict__ b2,
    const float* __restrict__ W3, const float* __restrict__ b3)
{
    __shared__ float xs[32][64];
    __shared__ float h1[32][256];
    __shared__ float h2[32][256];

    const int t  = threadIdx.x;
    const int r0 = blockIdx.x * 32;

    // stage X tile (32x64)
    {
        const int r = t >> 3;
        const int c = (t & 7) * 8;
        const size_t base = (size_t)(r0 + r) * DD + c;
        float4 v0 = *reinterpret_cast<const float4*>(&X[base]);
        float4 v1 = *reinterpret_cast<const float4*>(&X[base + 4]);
        *reinterpret_cast<float4*>(&xs[r][c])     = v0;
        *reinterpret_cast<float4*>(&xs[r][c + 4]) = v1;
    }
    __syncthreads();

    const int tc = t & 31;   // 8 output cols at 8*tc
    const int tr = t >> 5;   // 4 rows at 4*tr

    // ---- layer 1: xs @ W1[64x256] + b1, relu -> h1 ----
    {
        float acc[4][8];
        float4 bb0 = *reinterpret_cast<const float4*>(&b1[8 * tc]);
        float4 bb1 = *reinterpret_cast<const float4*>(&b1[8 * tc + 4]);
        #pragma unroll
        for (int rr = 0; rr < 4; ++rr) {
            acc[rr][0] = bb0.x; acc[rr][1] = bb0.y; acc[rr][2] = bb0.z; acc[rr][3] = bb0.w;
            acc[rr][4] = bb1.x; acc[rr][5] = bb1.y; acc[rr][6] = bb1.z; acc[rr][7] = bb1.w;
        }
        for (int d0 = 0; d0 < DD; d0 += 4) {
            float4 a[4];
            #pragma unroll
            for (int rr = 0; rr < 4; ++rr)
                a[rr] = *reinterpret_cast<const float4*>(&xs[4 * tr + rr][d0]);
            #pragma unroll
            for (int m = 0; m < 4; ++m) {
                const float* wrow = &W1[(size_t)(d0 + m) * HH + 8 * tc];
                float4 w0 = *reinterpret_cast<const float4*>(wrow);
                float4 w1 = *reinterpret_cast<const float4*>(wrow + 4);
                #pragma unroll
                for (int rr = 0; rr < 4; ++rr) {
                    const float av = (m == 0) ? a[rr].x : (m == 1) ? a[rr].y
                                   : (m == 2) ? a[rr].z : a[rr].w;
                    acc[rr][0] += av * w0.x; acc[rr][1] += av * w0.y;
                    acc[rr][2] += av * w0.z; acc[rr][3] += av * w0.w;
                    acc[rr][4] += av * w1.x; acc[rr][5] += av * w1.y;
                    acc[rr][6] += av * w1.z; acc[rr][7] += av * w1.w;
                }
            }
        }
        #pragma unroll
        for (int rr = 0; rr < 4; ++rr) {
            float4 o0, o1;
            o0.x = fmaxf(acc[rr][0], 0.f); o0.y = fmaxf(acc[rr][1], 0.f);
            o0.z = fmaxf(acc[rr][2], 0.f); o0.w = fmaxf(acc[rr][3], 0.f);
            o1.x = fmaxf(acc[rr][4], 0.f); o1.y = fmaxf(acc[rr][5], 0.f);
            o1.z = fmaxf(acc[rr][6], 0.f); o1.w = fmaxf(acc[rr][7], 0.f);
            *reinterpret_cast<float4*>(&h1[4 * tr + rr][8 * tc])     = o0;
            *reinterpret_cast<float4*>(&h1[4 * tr + rr][8 * tc + 4]) = o1;
        }
    }
    __syncthreads();

    // ---- layer 2: h1 @ W2[256x256] + b2, relu -> h2 ----
    {
        float acc[4][8];
        float4 bb0 = *reinterpret_cast<const float4*>(&b2[8 * tc]);
        float4 bb1 = *reinterpret_cast<const float4*>(&b2[8 * tc + 4]);
        #pragma unroll
        for (int rr = 0; rr < 4; ++rr) {
            acc[rr][0] = bb0.x; acc[rr][1] = bb0.y; acc[rr][2] = bb0.z; acc[rr][3] = bb0.w;
            acc[rr][4] = bb1.x; acc[rr][5] = bb1.y; acc[rr][6] = bb1.z; acc[rr][7] = bb1.w;
        }
        for (int d0 = 0; d0 < HH; d0 += 4) {
            float4 a[4];
            #pragma unroll
            for (int rr = 0; rr < 4; ++rr)
                a[rr] = *reinterpret_cast<const float4*>(&h1[4 * tr + rr][d0]);
            #pragma unroll
            for (int m = 0; m < 4; ++m) {
                const float* wrow = &W2[(size_t)(d0 + m) * HH + 8 * tc];
                float4 w0 = *reinterpret_cast<const float4*>(wrow);
                float4 w1 = *reinterpret_cast<const float4*>(wrow + 4);
                #pragma unroll
                for (int rr = 0; rr < 4; ++rr) {
                    const float av = (m == 0) ? a[rr].x : (m == 1) ? a[rr].y
                                   : (m == 2) ? a[rr].z : a[rr].w;
                    acc[rr][0] += av * w0.x; acc[rr][1] += av * w0.y;
                    acc[rr][2] += av * w0.z; acc[rr][3] += av * w0.w;
                    acc[rr][4] += av * w1.x; acc[rr][5] += av * w1.y;
                    acc[rr][6] += av * w1.z; acc[rr][7] += av * w1.w;
                }
            }
        }
        #pragma unroll
        for (int rr = 0; rr < 4; ++rr) {
            float4 o0, o1;
            o0.x = fmaxf(acc[rr][0], 0.f); o0.y = fmaxf(acc[rr][1], 0.f);
            o0.z = fmaxf(acc[rr][2], 0.f); o0.w = fmaxf(acc[rr][3], 0.f);
            o1.x = fmaxf(acc[rr][4], 0.f); o1.y = fmaxf(acc[rr][5], 0.f);
            o1.z = fmaxf(acc[rr][6], 0.f); o1.w = fmaxf(acc[rr][7], 0.f);
            *reinterpret_cast<float4*>(&h2[4 * tr + rr][8 * tc])     = o0;
            *reinterpret_cast<float4*>(&h2[4 * tr + rr][8 * tc + 4]) = o1;
        }
    }
    __syncthreads();

    // ---- layer 3: h2 @ W3[256x64] + b3 -> Y ----
    {
        const int j   = t & 63;
        const int tr2 = t >> 6;    // 8 rows at 8*tr2
        float acc[8];
        const float bv = b3[j];
        #pragma unroll
        for (int rr = 0; rr < 8; ++rr) acc[rr] = bv;
        for (int d0 = 0; d0 < HH; d0 += 4) {
            const float w0  = W3[(size_t)(d0 + 0) * DD + j];
            const float w1  = W3[(size_t)(d0 + 1) * DD + j];
            const float w2  = W3[(size_t)(d0 + 2) * DD + j];
            const float w3v = W3[(size_t)(d0 + 3) * DD + j];
            #pragma unroll
            for (int rr = 0; rr < 8; ++rr) {
                float4 a = *reinterpret_cast<const float4*>(&h2[8 * tr2 + rr][d0]);
                acc[rr] += a.x * w0 + a.y * w1 + a.z * w2 + a.w * w3v;
            }
        }
        #pragma unroll
        for (int rr = 0; rr < 8; ++rr)
            Y[(size_t)(r0 + 8 * tr2 + rr) * DD + j] = acc[rr];
    }
}

// ---------------------------------------------------------------------------
// Pass A: per key-row i, online softmax stats over the query axis k:
//   m_i = max_k dist[i,k],  l_i = sum_k exp(dist[i,k]-m_i),
//   dist[i,k] = (Wk[i] . Wq[k]) / 8
// Block: batch b, 32 i-rows (wave w owns 8 rows, its 64 lanes cover a k-tile).
// ---------------------------------------------------------------------------
__global__ __launch_bounds__(256, 4) void attn_stats_kernel(
    const float* __restrict__ Wk, const float* __restrict__ Wq,
    float* __restrict__ m_g, float* __restrict__ l_g)
{
    __shared__ float wk[32][68];
    __shared__ float wq[64][68];

    const int t  = threadIdx.x;
    const int b  = blockIdx.y;
    const int i0 = blockIdx.x * 32;
    const float* Wkb = Wk + (size_t)b * NTOK * DD;
    const float* Wqb = Wq + (size_t)b * NTOK * DD;

    {   // stage Wk i-tile (32x64)
        const int r = t >> 3;
        const int c = (t & 7) * 8;
        float4 v0 = *reinterpret_cast<const float4*>(&Wkb[(size_t)(i0 + r) * DD + c]);
        float4 v1 = *reinterpret_cast<const float4*>(&Wkb[(size_t)(i0 + r) * DD + c + 4]);
        *reinterpret_cast<float4*>(&wk[r][c])     = v0;
        *reinterpret_cast<float4*>(&wk[r][c + 4]) = v1;
    }

    const int tc = t & 63;   // k lane
    const int tr = t >> 6;   // wave id: rows 8*tr .. 8*tr+7

    float m[8], l[8];
    #pragma unroll
    for (int rr = 0; rr < 8; ++rr) { m[rr] = -INFINITY; l[rr] = 0.f; }

    for (int k0 = 0; k0 < NTOK; k0 += 64) {
        __syncthreads();
        {   // stage Wq k-tile (64x64)
            const int r = t >> 2;
            const int c = (t & 3) * 16;
            const float* src = &Wqb[(size_t)(k0 + r) * DD + c];
            float4 v0 = *reinterpret_cast<const float4*>(src);
            float4 v1 = *reinterpret_cast<const float4*>(src + 4);
            float4 v2 = *reinterpret_cast<const float4*>(src + 8);
            float4 v3 = *reinterpret_cast<const float4*>(src + 12);
            *reinterpret_cast<float4*>(&wq[r][c])      = v0;
            *reinterpret_cast<float4*>(&wq[r][c + 4])  = v1;
            *reinterpret_cast<float4*>(&wq[r][c + 8])  = v2;
            *reinterpret_cast<float4*>(&wq[r][c + 12]) = v3;
        }
        __syncthreads();

        float s[8];
        #pragma unroll
        for (int rr = 0; rr < 8; ++rr) s[rr] = 0.f;
        for (int d0 = 0; d0 < DD; d0 += 4) {
            float4 w = *reinterpret_cast<const float4*>(&wq[tc][d0]);
            #pragma unroll
            for (int rr = 0; rr < 8; ++rr) {
                float4 a = *reinterpret_cast<const float4*>(&wk[8 * tr + rr][d0]);
                s[rr] += a.x * w.x + a.y * w.y + a.z * w.z + a.w * w.w;
            }
        }
        #pragma unroll
        for (int rr = 0; rr < 8; ++rr) {
            const float v = s[rr] * 0.125f;
            float tmax = v;
            #pragma unroll
            for (int off = 32; off > 0; off >>= 1)
                tmax = fmaxf(tmax, __shfl_xor(tmax, off));
            const float mn = fmaxf(m[rr], tmax);
            float ps = __expf(v - mn);
            #pragma unroll
            for (int off = 32; off > 0; off >>= 1)
                ps += __shfl_xor(ps, off);
            l[rr] = l[rr] * __expf(m[rr] - mn) + ps;
            m[rr] = mn;
        }
    }

    if (tc == 0) {
        #pragma unroll
        for (int rr = 0; rr < 8; ++rr) {
            const size_t idx = (size_t)b * NTOK + i0 + 8 * tr + rr;
            m_g[idx] = m[rr];
            l_g[idx] = l[rr];
        }
    }
}

// ---------------------------------------------------------------------------
// Pass B: context[b,k,j] = sum_i exp(dist[i,k]-m_i)/l_i * Wv[i,j]
// Block: batch b, 32 output rows k. Loop i-tiles of 64: recompute dist,
// P tile -> LDS, then accumulate P^T @ Wv into registers.
// ---------------------------------------------------------------------------
__global__ __launch_bounds__(256, 2) void attn_context_kernel(
    const float* __restrict__ Wk, const float* __restrict__ Wq,
    const float* __restrict__ Wv,
    const float* __restrict__ m_g, const float* __restrict__ l_g,
    float* __restrict__ out)
{
    __shared__ float wq[32][68];
    __shared__ float wk[64][68];
    __shared__ float wv[64][68];
    __shared__ float pp[64][36];
    __shared__ float ms[64];
    __shared__ float rls[64];

    const int t  = threadIdx.x;
    const int b  = blockIdx.y;
    const int k0 = blockIdx.x * 32;
    const float* Wkb = Wk + (size_t)b * NTOK * DD;
    const float* Wqb = Wq + (size_t)b * NTOK * DD;
    const float* Wvb = Wv + (size_t)b * NTOK * DD;

    {   // stage Wq k-tile (32x64), once
        const int r = t >> 3;
        const int c = (t & 7) * 8;
        float4 v0 = *reinterpret_cast<const float4*>(&Wqb[(size_t)(k0 + r) * DD + c]);
        float4 v1 = *reinterpret_cast<const float4*>(&Wqb[(size_t)(k0 + r) * DD + c + 4]);
        *reinterpret_cast<float4*>(&wq[r][c])     = v0;
        *reinterpret_cast<float4*>(&wq[r][c + 4]) = v1;
    }

    const int p_tc = t & 31;   // k col within tile (phase 1)
    const int p_tr = t >> 5;   // i rows 8*p_tr..+7 (phase 1)
    const int q_j  = t & 63;   // dv col (phase 2)
    const int q_tr = t >> 6;   // k rows 8*q_tr..+7 (phase 2)

    float acc[8];
    #pragma unroll
    for (int rr = 0; rr < 8; ++rr) acc[rr] = 0.f;

    for (int i0 = 0; i0 < NTOK; i0 += 64) {
        __syncthreads();
        {   // stage Wk and Wv i-tiles (64x64 each)
            const int r = t >> 2;
            const int c = (t & 3) * 16;
            const float* srck = &Wkb[(size_t)(i0 + r) * DD + c];
            const float* srcv = &Wvb[(size_t)(i0 + r) * DD + c];
            float4 k0v = *reinterpret_cast<const float4*>(srck);
            float4 k1v = *reinterpret_cast<const float4*>(srck + 4);
            float4 k2v = *reinterpret_cast<const float4*>(srck + 8);
            float4 k3v = *reinterpret_cast<const float4*>(srck + 12);
            float4 v0v = *reinterpret_cast<const float4*>(srcv);
            float4 v1v = *reinterpret_cast<const float4*>(srcv + 4);
            float4 v2v = *reinterpret_cast<const float4*>(srcv + 8);
            float4 v3v = *reinterpret_cast<const float4*>(srcv + 12);
            *reinterpret_cast<float4*>(&wk[r][c])      = k0v;
            *reinterpret_cast<float4*>(&wk[r][c + 4])  = k1v;
            *reinterpret_cast<float4*>(&wk[r][c + 8])  = k2v;
            *reinterpret_cast<float4*>(&wk[r][c + 12]) = k3v;
            *reinterpret_cast<float4*>(&wv[r][c])      = v0v;
            *reinterpret_cast<float4*>(&wv[r][c + 4])  = v1v;
            *reinterpret_cast<float4*>(&wv[r][c + 8])  = v2v;
            *reinterpret_cast<float4*>(&wv[r][c + 12]) = v3v;
        }
        if (t < 64) {
            const size_t idx = (size_t)b * NTOK + i0 + t;
            ms[t]  = m_g[idx];
            rls[t] = 1.0f / l_g[idx];
        }
        __syncthreads();

        // phase 1: dist tile + P -> LDS
        float s[8];
        #pragma unroll
        for (int rr = 0; rr < 8; ++rr) s[rr] = 0.f;
        for (int d0 = 0; d0 < DD; d0 += 4) {
            float4 w = *reinterpret_cast<const float4*>(&wq[p_tc][d0]);
            #pragma unroll
            for (int rr = 0; rr < 8; ++rr) {
                float4 a = *reinterpret_cast<const float4*>(&wk[8 * p_tr + rr][d0]);
                s[rr] += a.x * w.x + a.y * w.y + a.z * w.z + a.w * w.w;
            }
        }
        #pragma unroll
        for (int rr = 0; rr < 8; ++rr) {
            const int i = 8 * p_tr + rr;
            pp[i][p_tc] = __expf(s[rr] * 0.125f - ms[i]) * rls[i];
        }
        __syncthreads();

        // phase 2: acc[k,:] += P^T @ Wv
        for (int i = 0; i < 64; ++i) {
            const float w = wv[i][q_j];
            float4 pa = *reinterpret_cast<const float4*>(&pp[i][8 * q_tr]);
            float4 pb = *reinterpret_cast<const float4*>(&pp[i][8 * q_tr + 4]);
            acc[0] += pa.x * w; acc[1] += pa.y * w;
            acc[2] += pa.z * w; acc[3] += pa.w * w;
            acc[4] += pb.x * w; acc[5] += pb.y * w;
            acc[6] += pb.z * w; acc[7] += pb.w * w;
        }
    }

    #pragma unroll
    for (int rr = 0; rr < 8; ++rr)
        out[((size_t)b * NTOK + k0 + 8 * q_tr + rr) * DD + q_j] = acc[rr];
}

// ---------------------------------------------------------------------------
extern "C" void kernel_launch(void* const* d_in, const int* in_sizes, int n_in,
                              void* d_out, int out_size, void* d_ws, size_t ws_size,
                              hipStream_t stream) {
    const float* KEY   = (const float*)d_in[0];
    const float* VALUE = (const float*)d_in[1];
    const float* QUERY = (const float*)d_in[2];
    const float* Wk1 = (const float*)d_in[3];
    const float* bk1 = (const float*)d_in[4];
    const float* Wk2 = (const float*)d_in[5];
    const float* bk2 = (const float*)d_in[6];
    const float* Wk3 = (const float*)d_in[7];
    const float* bk3 = (const float*)d_in[8];
    const float* Wv1 = (const float*)d_in[9];
    const float* bv1 = (const float*)d_in[10];
    const float* Wv2 = (const float*)d_in[11];
    const float* bv2 = (const float*)d_in[12];
    const float* Wv3 = (const float*)d_in[13];
    const float* bv3 = (const float*)d_in[14];

    float* ws  = (float*)d_ws;
    float* WkO = ws;                                 // 16384*64
    float* WqO = WkO + (size_t)NROWS * DD;
    float* WvO = WqO + (size_t)NROWS * DD;
    float* m_g = WvO + (size_t)NROWS * DD;           // 16384
    float* l_g = m_g + NROWS;                        // 16384

    mlp_kernel<<<NROWS / 32, 256, 0, stream>>>(KEY,   WkO, Wk1, bk1, Wk2, bk2, Wk3, bk3);
    mlp_kernel<<<NROWS / 32, 256, 0, stream>>>(QUERY, WqO, Wk1, bk1, Wk2, bk2, Wk3, bk3);
    mlp_kernel<<<NROWS / 32, 256, 0, stream>>>(VALUE, WvO, Wv1, bv1, Wv2, bv2, Wv3, bv3);

    attn_stats_kernel<<<dim3(NTOK / 32, NB), 256, 0, stream>>>(WkO, WqO, m_g, l_g);
    attn_context_kernel<<<dim3(NTOK / 32, NB), 256, 0, stream>>>(WkO, WqO, WvO, m_g, l_g,
                                                                 (float*)d_out);
}

// Round 7
// 609.559 us; speedup vs baseline: 1.1214x; 1.1214x over previous
//
#include <hip/hip_runtime.h>
#include <math.h>

#define NB 8
#define NTOK 2048
#define DD 64
#define HH 256
#define NROWS (NB * NTOK)   // 16384

// softmax in exp2 domain: e^x == 2^(x*log2e); logits scaled once by 0.125*log2(e)
#define SCALE2 0.18033688011112042f

// exp2f: HIP device overload; OCML lowers this to the native v_exp_f32
#define EXP2F(x) exp2f(x)

// ---------------------------------------------------------------------------
// Fused 3-layer MLP:  Y[rows,64] = relu(relu(X@W1+b1)@W2+b2)@W3+b3
// 32-row tile per block, 256 threads. Activations in LDS (broadcast reads),
// weights streamed from global (L2-resident: 384 KB total).
// ---------------------------------------------------------------------------
__global__ __launch_bounds__(256, 2) void mlp_kernel(
    const float* __restrict__ X, float* __restrict__ Y,
    const float* __restrict__ W1, const float* __restrict__ b1,
    const float* __restrict__ W2, const float* __restrict__ b2,
    const float* __restrict__ W3, const float* __restrict__ b3)
{
    __shared__ float xs[32][64];
    __shared__ float h1[32][256];
    __shared__ float h2[32][256];

    const int t  = threadIdx.x;
    const int r0 = blockIdx.x * 32;

    // stage X tile (32x64)
    {
        const int r = t >> 3;
        const int c = (t & 7) * 8;
        const size_t base = (size_t)(r0 + r) * DD + c;
        float4 v0 = *reinterpret_cast<const float4*>(&X[base]);
        float4 v1 = *reinterpret_cast<const float4*>(&X[base + 4]);
        *reinterpret_cast<float4*>(&xs[r][c])     = v0;
        *reinterpret_cast<float4*>(&xs[r][c + 4]) = v1;
    }
    __syncthreads();

    const int tc = t & 31;   // 8 output cols at 8*tc
    const int tr = t >> 5;   // 4 rows at 4*tr

    // ---- layer 1: xs @ W1[64x256] + b1, relu -> h1 ----
    {
        float acc[4][8];
        float4 bb0 = *reinterpret_cast<const float4*>(&b1[8 * tc]);
        float4 bb1 = *reinterpret_cast<const float4*>(&b1[8 * tc + 4]);
        #pragma unroll
        for (int rr = 0; rr < 4; ++rr) {
            acc[rr][0] = bb0.x; acc[rr][1] = bb0.y; acc[rr][2] = bb0.z; acc[rr][3] = bb0.w;
            acc[rr][4] = bb1.x; acc[rr][5] = bb1.y; acc[rr][6] = bb1.z; acc[rr][7] = bb1.w;
        }
        for (int d0 = 0; d0 < DD; d0 += 4) {
            float4 a[4];
            #pragma unroll
            for (int rr = 0; rr < 4; ++rr)
                a[rr] = *reinterpret_cast<const float4*>(&xs[4 * tr + rr][d0]);
            #pragma unroll
            for (int m = 0; m < 4; ++m) {
                const float* wrow = &W1[(size_t)(d0 + m) * HH + 8 * tc];
                float4 w0 = *reinterpret_cast<const float4*>(wrow);
                float4 w1 = *reinterpret_cast<const float4*>(wrow + 4);
                #pragma unroll
                for (int rr = 0; rr < 4; ++rr) {
                    const float av = (m == 0) ? a[rr].x : (m == 1) ? a[rr].y
                                   : (m == 2) ? a[rr].z : a[rr].w;
                    acc[rr][0] += av * w0.x; acc[rr][1] += av * w0.y;
                    acc[rr][2] += av * w0.z; acc[rr][3] += av * w0.w;
                    acc[rr][4] += av * w1.x; acc[rr][5] += av * w1.y;
                    acc[rr][6] += av * w1.z; acc[rr][7] += av * w1.w;
                }
            }
        }
        #pragma unroll
        for (int rr = 0; rr < 4; ++rr) {
            float4 o0, o1;
            o0.x = fmaxf(acc[rr][0], 0.f); o0.y = fmaxf(acc[rr][1], 0.f);
            o0.z = fmaxf(acc[rr][2], 0.f); o0.w = fmaxf(acc[rr][3], 0.f);
            o1.x = fmaxf(acc[rr][4], 0.f); o1.y = fmaxf(acc[rr][5], 0.f);
            o1.z = fmaxf(acc[rr][6], 0.f); o1.w = fmaxf(acc[rr][7], 0.f);
            *reinterpret_cast<float4*>(&h1[4 * tr + rr][8 * tc])     = o0;
            *reinterpret_cast<float4*>(&h1[4 * tr + rr][8 * tc + 4]) = o1;
        }
    }
    __syncthreads();

    // ---- layer 2: h1 @ W2[256x256] + b2, relu -> h2 ----
    {
        float acc[4][8];
        float4 bb0 = *reinterpret_cast<const float4*>(&b2[8 * tc]);
        float4 bb1 = *reinterpret_cast<const float4*>(&b2[8 * tc + 4]);
        #pragma unroll
        for (int rr = 0; rr < 4; ++rr) {
            acc[rr][0] = bb0.x; acc[rr][1] = bb0.y; acc[rr][2] = bb0.z; acc[rr][3] = bb0.w;
            acc[rr][4] = bb1.x; acc[rr][5] = bb1.y; acc[rr][6] = bb1.z; acc[rr][7] = bb1.w;
        }
        for (int d0 = 0; d0 < HH; d0 += 4) {
            float4 a[4];
            #pragma unroll
            for (int rr = 0; rr < 4; ++rr)
                a[rr] = *reinterpret_cast<const float4*>(&h1[4 * tr + rr][d0]);
            #pragma unroll
            for (int m = 0; m < 4; ++m) {
                const float* wrow = &W2[(size_t)(d0 + m) * HH + 8 * tc];
                float4 w0 = *reinterpret_cast<const float4*>(wrow);
                float4 w1 = *reinterpret_cast<const float4*>(wrow + 4);
                #pragma unroll
                for (int rr = 0; rr < 4; ++rr) {
                    const float av = (m == 0) ? a[rr].x : (m == 1) ? a[rr].y
                                   : (m == 2) ? a[rr].z : a[rr].w;
                    acc[rr][0] += av * w0.x; acc[rr][1] += av * w0.y;
                    acc[rr][2] += av * w0.z; acc[rr][3] += av * w0.w;
                    acc[rr][4] += av * w1.x; acc[rr][5] += av * w1.y;
                    acc[rr][6] += av * w1.z; acc[rr][7] += av * w1.w;
                }
            }
        }
        #pragma unroll
        for (int rr = 0; rr < 4; ++rr) {
            float4 o0, o1;
            o0.x = fmaxf(acc[rr][0], 0.f); o0.y = fmaxf(acc[rr][1], 0.f);
            o0.z = fmaxf(acc[rr][2], 0.f); o0.w = fmaxf(acc[rr][3], 0.f);
            o1.x = fmaxf(acc[rr][4], 0.f); o1.y = fmaxf(acc[rr][5], 0.f);
            o1.z = fmaxf(acc[rr][6], 0.f); o1.w = fmaxf(acc[rr][7], 0.f);
            *reinterpret_cast<float4*>(&h2[4 * tr + rr][8 * tc])     = o0;
            *reinterpret_cast<float4*>(&h2[4 * tr + rr][8 * tc + 4]) = o1;
        }
    }
    __syncthreads();

    // ---- layer 3: h2 @ W3[256x64] + b3 -> Y ----
    {
        const int j   = t & 63;
        const int tr2 = t >> 6;    // 8 rows at 8*tr2
        float acc[8];
        const float bv = b3[j];
        #pragma unroll
        for (int rr = 0; rr < 8; ++rr) acc[rr] = bv;
        for (int d0 = 0; d0 < HH; d0 += 4) {
            const float w0  = W3[(size_t)(d0 + 0) * DD + j];
            const float w1  = W3[(size_t)(d0 + 1) * DD + j];
            const float w2  = W3[(size_t)(d0 + 2) * DD + j];
            const float w3v = W3[(size_t)(d0 + 3) * DD + j];
            #pragma unroll
            for (int rr = 0; rr < 8; ++rr) {
                float4 a = *reinterpret_cast<const float4*>(&h2[8 * tr2 + rr][d0]);
                acc[rr] += a.x * w0 + a.y * w1 + a.z * w2 + a.w * w3v;
            }
        }
        #pragma unroll
        for (int rr = 0; rr < 8; ++rr)
            Y[(size_t)(r0 + 8 * tr2 + rr) * DD + j] = acc[rr];
    }
}

// ---------------------------------------------------------------------------
// Pass A: per key-row i, online softmax stats over the query axis k
// (exp2 domain). Per-lane online (m,l); ONE wave reduction at the end.
// ---------------------------------------------------------------------------
__global__ __launch_bounds__(256, 4) void attn_stats_kernel(
    const float* __restrict__ Wk, const float* __restrict__ Wq,
    float* __restrict__ m_g, float* __restrict__ l_g)
{
    __shared__ float wk[32][68];
    __shared__ float wq[64][68];

    const int t  = threadIdx.x;
    const int b  = blockIdx.y;
    const int i0 = blockIdx.x * 32;
    const float* Wkb = Wk + (size_t)b * NTOK * DD;
    const float* Wqb = Wq + (size_t)b * NTOK * DD;

    {   // stage Wk i-tile (32x64)
        const int r = t >> 3;
        const int c = (t & 7) * 8;
        float4 v0 = *reinterpret_cast<const float4*>(&Wkb[(size_t)(i0 + r) * DD + c]);
        float4 v1 = *reinterpret_cast<const float4*>(&Wkb[(size_t)(i0 + r) * DD + c + 4]);
        *reinterpret_cast<float4*>(&wk[r][c])     = v0;
        *reinterpret_cast<float4*>(&wk[r][c + 4]) = v1;
    }

    const int tc = t & 63;   // k lane
    const int tr = t >> 6;   // wave id: rows 8*tr .. 8*tr+7

    float m[8], l[8];        // per-lane online stats over this lane's k subset
    #pragma unroll
    for (int rr = 0; rr < 8; ++rr) { m[rr] = -INFINITY; l[rr] = 0.f; }

    for (int k0 = 0; k0 < NTOK; k0 += 64) {
        __syncthreads();
        {   // stage Wq k-tile (64x64)
            const int r = t >> 2;
            const int c = (t & 3) * 16;
            const float* src = &Wqb[(size_t)(k0 + r) * DD + c];
            float4 v0 = *reinterpret_cast<const float4*>(src);
            float4 v1 = *reinterpret_cast<const float4*>(src + 4);
            float4 v2 = *reinterpret_cast<const float4*>(src + 8);
            float4 v3 = *reinterpret_cast<const float4*>(src + 12);
            *reinterpret_cast<float4*>(&wq[r][c])      = v0;
            *reinterpret_cast<float4*>(&wq[r][c + 4])  = v1;
            *reinterpret_cast<float4*>(&wq[r][c + 8])  = v2;
            *reinterpret_cast<float4*>(&wq[r][c + 12]) = v3;
        }
        __syncthreads();

        float s[8];
        #pragma unroll
        for (int rr = 0; rr < 8; ++rr) s[rr] = 0.f;
        for (int d0 = 0; d0 < DD; d0 += 4) {
            float4 w = *reinterpret_cast<const float4*>(&wq[tc][d0]);
            #pragma unroll
            for (int rr = 0; rr < 8; ++rr) {
                float4 a = *reinterpret_cast<const float4*>(&wk[8 * tr + rr][d0]);
                s[rr] += a.x * w.x + a.y * w.y + a.z * w.z + a.w * w.w;
            }
        }
        // per-lane online update: 1 exp2 per row per tile
        #pragma unroll
        for (int rr = 0; rr < 8; ++rr) {
            const float v = s[rr] * SCALE2;
            const float d = v - m[rr];
            const float e = EXP2F(-fabsf(d));
            if (d <= 0.f) {
                l[rr] += e;                 // v <= m: add exp2(v-m)
            } else {
                l[rr] = l[rr] * e + 1.f;    // rescale old sum, add exp2(0)
                m[rr] = v;
            }
        }
    }

    // one final wave-wide (m,l) combine per row
    #pragma unroll
    for (int rr = 0; rr < 8; ++rr) {
        float mm = m[rr], ll = l[rr];
        #pragma unroll
        for (int off = 32; off > 0; off >>= 1) {
            const float mo = __shfl_xor(mm, off);
            const float lo = __shfl_xor(ll, off);
            const float e  = EXP2F(-fabsf(mm - mo));
            if (mm >= mo) {
                ll = ll + lo * e;
            } else {
                ll = ll * e + lo;
                mm = mo;
            }
        }
        if (tc == 0) {
            const size_t idx = (size_t)b * NTOK + i0 + 8 * tr + rr;
            m_g[idx] = mm;    // exp2-domain max
            l_g[idx] = ll;
        }
    }
}

// ---------------------------------------------------------------------------
// Pass B: context[b,k,j] = sum_i exp2(v2[i,k]-m_i)/l_i * Wv[i,j]
// ---------------------------------------------------------------------------
__global__ __launch_bounds__(256, 2) void attn_context_kernel(
    const float* __restrict__ Wk, const float* __restrict__ Wq,
    const float* __restrict__ Wv,
    const float* __restrict__ m_g, const float* __restrict__ l_g,
    float* __restrict__ out)
{
    __shared__ float wq[32][68];
    __shared__ float wk[64][68];
    __shared__ float wv[64][68];
    __shared__ float pp[64][36];
    __shared__ float ms[64];
    __shared__ float rls[64];

    const int t  = threadIdx.x;
    const int b  = blockIdx.y;
    const int k0 = blockIdx.x * 32;
    const float* Wkb = Wk + (size_t)b * NTOK * DD;
    const float* Wqb = Wq + (size_t)b * NTOK * DD;
    const float* Wvb = Wv + (size_t)b * NTOK * DD;

    {   // stage Wq k-tile (32x64), once
        const int r = t >> 3;
        const int c = (t & 7) * 8;
        float4 v0 = *reinterpret_cast<const float4*>(&Wqb[(size_t)(k0 + r) * DD + c]);
        float4 v1 = *reinterpret_cast<const float4*>(&Wqb[(size_t)(k0 + r) * DD + c + 4]);
        *reinterpret_cast<float4*>(&wq[r][c])     = v0;
        *reinterpret_cast<float4*>(&wq[r][c + 4]) = v1;
    }

    const int p_tc = t & 31;   // k col within tile (phase 1)
    const int p_tr = t >> 5;   // i rows 8*p_tr..+7 (phase 1)
    const int q_j  = t & 63;   // dv col (phase 2)
    const int q_tr = t >> 6;   // k rows 8*q_tr..+7 (phase 2)

    float acc[8];
    #pragma unroll
    for (int rr = 0; rr < 8; ++rr) acc[rr] = 0.f;

    for (int i0 = 0; i0 < NTOK; i0 += 64) {
        __syncthreads();
        {   // stage Wk and Wv i-tiles (64x64 each)
            const int r = t >> 2;
            const int c = (t & 3) * 16;
            const float* srck = &Wkb[(size_t)(i0 + r) * DD + c];
            const float* srcv = &Wvb[(size_t)(i0 + r) * DD + c];
            float4 k0v = *reinterpret_cast<const float4*>(srck);
            float4 k1v = *reinterpret_cast<const float4*>(srck + 4);
            float4 k2v = *reinterpret_cast<const float4*>(srck + 8);
            float4 k3v = *reinterpret_cast<const float4*>(srck + 12);
            float4 v0v = *reinterpret_cast<const float4*>(srcv);
            float4 v1v = *reinterpret_cast<const float4*>(srcv + 4);
            float4 v2v = *reinterpret_cast<const float4*>(srcv + 8);
            float4 v3v = *reinterpret_cast<const float4*>(srcv + 12);
            *reinterpret_cast<float4*>(&wk[r][c])      = k0v;
            *reinterpret_cast<float4*>(&wk[r][c + 4])  = k1v;
            *reinterpret_cast<float4*>(&wk[r][c + 8])  = k2v;
            *reinterpret_cast<float4*>(&wk[r][c + 12]) = k3v;
            *reinterpret_cast<float4*>(&wv[r][c])      = v0v;
            *reinterpret_cast<float4*>(&wv[r][c + 4])  = v1v;
            *reinterpret_cast<float4*>(&wv[r][c + 8])  = v2v;
            *reinterpret_cast<float4*>(&wv[r][c + 12]) = v3v;
        }
        if (t < 64) {
            const size_t idx = (size_t)b * NTOK + i0 + t;
            ms[t]  = m_g[idx];
            rls[t] = 1.0f / l_g[idx];
        }
        __syncthreads();

        // phase 1: dist tile + P -> LDS
        float s[8];
        #pragma unroll
        for (int rr = 0; rr < 8; ++rr) s[rr] = 0.f;
        for (int d0 = 0; d0 < DD; d0 += 4) {
            float4 w = *reinterpret_cast<const float4*>(&wq[p_tc][d0]);
            #pragma unroll
            for (int rr = 0; rr < 8; ++rr) {
                float4 a = *reinterpret_cast<const float4*>(&wk[8 * p_tr + rr][d0]);
                s[rr] += a.x * w.x + a.y * w.y + a.z * w.z + a.w * w.w;
            }
        }
        #pragma unroll
        for (int rr = 0; rr < 8; ++rr) {
            const int i = 8 * p_tr + rr;
            pp[i][p_tc] = EXP2F(s[rr] * SCALE2 - ms[i]) * rls[i];
        }
        __syncthreads();

        // phase 2: acc[k,:] += P^T @ Wv
        for (int i = 0; i < 64; ++i) {
            const float w = wv[i][q_j];
            float4 pa = *reinterpret_cast<const float4*>(&pp[i][8 * q_tr]);
            float4 pb = *reinterpret_cast<const float4*>(&pp[i][8 * q_tr + 4]);
            acc[0] += pa.x * w; acc[1] += pa.y * w;
            acc[2] += pa.z * w; acc[3] += pa.w * w;
            acc[4] += pb.x * w; acc[5] += pb.y * w;
            acc[6] += pb.z * w; acc[7] += pb.w * w;
        }
    }

    #pragma unroll
    for (int rr = 0; rr < 8; ++rr)
        out[((size_t)b * NTOK + k0 + 8 * q_tr + rr) * DD + q_j] = acc[rr];
}

// ---------------------------------------------------------------------------
extern "C" void kernel_launch(void* const* d_in, const int* in_sizes, int n_in,
                              void* d_out, int out_size, void* d_ws, size_t ws_size,
                              hipStream_t stream) {
    const float* KEY   = (const float*)d_in[0];
    const float* VALUE = (const float*)d_in[1];
    const float* QUERY = (const float*)d_in[2];
    const float* Wk1 = (const float*)d_in[3];
    const float* bk1 = (const float*)d_in[4];
    const float* Wk2 = (const float*)d_in[5];
    const float* bk2 = (const float*)d_in[6];
    const float* Wk3 = (const float*)d_in[7];
    const float* bk3 = (const float*)d_in[8];
    const float* Wv1 = (const float*)d_in[9];
    const float* bv1 = (const float*)d_in[10];
    const float* Wv2 = (const float*)d_in[11];
    const float* bv2 = (const float*)d_in[12];
    const float* Wv3 = (const float*)d_in[13];
    const float* bv3 = (const float*)d_in[14];

    float* ws  = (float*)d_ws;
    float* WkO = ws;                                 // 16384*64
    float* WqO = WkO + (size_t)NROWS * DD;
    float* WvO = WqO + (size_t)NROWS * DD;
    float* m_g = WvO + (size_t)NROWS * DD;           // 16384
    float* l_g = m_g + NROWS;                        // 16384

    mlp_kernel<<<NROWS / 32, 256, 0, stream>>>(KEY,   WkO, Wk1, bk1, Wk2, bk2, Wk3, bk3);
    mlp_kernel<<<NROWS / 32, 256, 0, stream>>>(QUERY, WqO, Wk1, bk1, Wk2, bk2, Wk3, bk3);
    mlp_kernel<<<NROWS / 32, 256, 0, stream>>>(VALUE, WvO, Wv1, bv1, Wv2, bv2, Wv3, bv3);

    attn_stats_kernel<<<dim3(NTOK / 32, NB), 256, 0, stream>>>(WkO, WqO, m_g, l_g);
    attn_context_kernel<<<dim3(NTOK / 32, NB), 256, 0, stream>>>(WkO, WqO, WvO, m_g, l_g,
                                                                 (float*)d_out);
}

// Round 12
// 400.304 us; speedup vs baseline: 1.7076x; 1.5227x over previous
//
#include <hip/hip_runtime.h>
#include <math.h>

#define NB 8
#define NTOK 2048
#define DD 64
#define HH 256
#define NROWS (NB * NTOK)   // 16384

// softmax in exp2 domain: e^x == 2^(x*log2e); logits scaled once by 0.125*log2(e)
#define SCALE2 0.18033688011112042f

typedef __attribute__((ext_vector_type(8))) short s8v;   // 8 bf16 (4 VGPRs) — MFMA A/B frag
typedef __attribute__((ext_vector_type(4))) float f4v;   // MFMA C/D frag

#define MFMA __builtin_amdgcn_mfma_f32_16x16x32_bf16

__device__ __forceinline__ ushort f2bf(float x) {        // fp32 -> bf16 (RNE)
    union { float f; unsigned u; } v; v.f = x;
    return (ushort)((v.u + 0x7FFFu + ((v.u >> 16) & 1u)) >> 16);
}
__device__ __forceinline__ float bf2f(ushort u) {
    union { unsigned u; float f; } v; v.u = ((unsigned)u) << 16; return v.f;
}

// ---------------------------------------------------------------------------
// Fused 3-layer MLP -> hi/lo split-bf16 output (row-major [row][64] ushort).
// ---------------------------------------------------------------------------
__global__ __launch_bounds__(256, 2) void mlp_kernel(
    const float* __restrict__ X, ushort* __restrict__ YH, ushort* __restrict__ YL,
    const float* __restrict__ W1, const float* __restrict__ b1,
    const float* __restrict__ W2, const float* __restrict__ b2,
    const float* __restrict__ W3, const float* __restrict__ b3)
{
    __shared__ float xs[32][64];
    __shared__ float h1[32][256];
    __shared__ float h2[32][256];

    const int t  = threadIdx.x;
    const int r0 = blockIdx.x * 32;

    {   // stage X tile (32x64)
        const int r = t >> 3;
        const int c = (t & 7) * 8;
        const size_t base = (size_t)(r0 + r) * DD + c;
        float4 v0 = *reinterpret_cast<const float4*>(&X[base]);
        float4 v1 = *reinterpret_cast<const float4*>(&X[base + 4]);
        *reinterpret_cast<float4*>(&xs[r][c])     = v0;
        *reinterpret_cast<float4*>(&xs[r][c + 4]) = v1;
    }
    __syncthreads();

    const int tc = t & 31;
    const int tr = t >> 5;

    // ---- layer 1 ----
    {
        float acc[4][8];
        float4 bb0 = *reinterpret_cast<const float4*>(&b1[8 * tc]);
        float4 bb1 = *reinterpret_cast<const float4*>(&b1[8 * tc + 4]);
        #pragma unroll
        for (int rr = 0; rr < 4; ++rr) {
            acc[rr][0] = bb0.x; acc[rr][1] = bb0.y; acc[rr][2] = bb0.z; acc[rr][3] = bb0.w;
            acc[rr][4] = bb1.x; acc[rr][5] = bb1.y; acc[rr][6] = bb1.z; acc[rr][7] = bb1.w;
        }
        for (int d0 = 0; d0 < DD; d0 += 4) {
            float4 a[4];
            #pragma unroll
            for (int rr = 0; rr < 4; ++rr)
                a[rr] = *reinterpret_cast<const float4*>(&xs[4 * tr + rr][d0]);
            #pragma unroll
            for (int m = 0; m < 4; ++m) {
                const float* wrow = &W1[(size_t)(d0 + m) * HH + 8 * tc];
                float4 w0 = *reinterpret_cast<const float4*>(wrow);
                float4 w1 = *reinterpret_cast<const float4*>(wrow + 4);
                #pragma unroll
                for (int rr = 0; rr < 4; ++rr) {
                    const float av = (m == 0) ? a[rr].x : (m == 1) ? a[rr].y
                                   : (m == 2) ? a[rr].z : a[rr].w;
                    acc[rr][0] += av * w0.x; acc[rr][1] += av * w0.y;
                    acc[rr][2] += av * w0.z; acc[rr][3] += av * w0.w;
                    acc[rr][4] += av * w1.x; acc[rr][5] += av * w1.y;
                    acc[rr][6] += av * w1.z; acc[rr][7] += av * w1.w;
                }
            }
        }
        #pragma unroll
        for (int rr = 0; rr < 4; ++rr) {
            float4 o0, o1;
            o0.x = fmaxf(acc[rr][0], 0.f); o0.y = fmaxf(acc[rr][1], 0.f);
            o0.z = fmaxf(acc[rr][2], 0.f); o0.w = fmaxf(acc[rr][3], 0.f);
            o1.x = fmaxf(acc[rr][4], 0.f); o1.y = fmaxf(acc[rr][5], 0.f);
            o1.z = fmaxf(acc[rr][6], 0.f); o1.w = fmaxf(acc[rr][7], 0.f);
            *reinterpret_cast<float4*>(&h1[4 * tr + rr][8 * tc])     = o0;
            *reinterpret_cast<float4*>(&h1[4 * tr + rr][8 * tc + 4]) = o1;
        }
    }
    __syncthreads();

    // ---- layer 2 ----
    {
        float acc[4][8];
        float4 bb0 = *reinterpret_cast<const float4*>(&b2[8 * tc]);
        float4 bb1 = *reinterpret_cast<const float4*>(&b2[8 * tc + 4]);
        #pragma unroll
        for (int rr = 0; rr < 4; ++rr) {
            acc[rr][0] = bb0.x; acc[rr][1] = bb0.y; acc[rr][2] = bb0.z; acc[rr][3] = bb0.w;
            acc[rr][4] = bb1.x; acc[rr][5] = bb1.y; acc[rr][6] = bb1.z; acc[rr][7] = bb1.w;
        }
        for (int d0 = 0; d0 < HH; d0 += 4) {
            float4 a[4];
            #pragma unroll
            for (int rr = 0; rr < 4; ++rr)
                a[rr] = *reinterpret_cast<const float4*>(&h1[4 * tr + rr][d0]);
            #pragma unroll
            for (int m = 0; m < 4; ++m) {
                const float* wrow = &W2[(size_t)(d0 + m) * HH + 8 * tc];
                float4 w0 = *reinterpret_cast<const float4*>(wrow);
                float4 w1 = *reinterpret_cast<const float4*>(wrow + 4);
                #pragma unroll
                for (int rr = 0; rr < 4; ++rr) {
                    const float av = (m == 0) ? a[rr].x : (m == 1) ? a[rr].y
                                   : (m == 2) ? a[rr].z : a[rr].w;
                    acc[rr][0] += av * w0.x; acc[rr][1] += av * w0.y;
                    acc[rr][2] += av * w0.z; acc[rr][3] += av * w0.w;
                    acc[rr][4] += av * w1.x; acc[rr][5] += av * w1.y;
                    acc[rr][6] += av * w1.z; acc[rr][7] += av * w1.w;
                }
            }
        }
        #pragma unroll
        for (int rr = 0; rr < 4; ++rr) {
            float4 o0, o1;
            o0.x = fmaxf(acc[rr][0], 0.f); o0.y = fmaxf(acc[rr][1], 0.f);
            o0.z = fmaxf(acc[rr][2], 0.f); o0.w = fmaxf(acc[rr][3], 0.f);
            o1.x = fmaxf(acc[rr][4], 0.f); o1.y = fmaxf(acc[rr][5], 0.f);
            o1.z = fmaxf(acc[rr][6], 0.f); o1.w = fmaxf(acc[rr][7], 0.f);
            *reinterpret_cast<float4*>(&h2[4 * tr + rr][8 * tc])     = o0;
            *reinterpret_cast<float4*>(&h2[4 * tr + rr][8 * tc + 4]) = o1;
        }
    }
    __syncthreads();

    // ---- layer 3 -> split bf16 ----
    {
        const int j   = t & 63;
        const int tr2 = t >> 6;
        float acc[8];
        const float bv = b3[j];
        #pragma unroll
        for (int rr = 0; rr < 8; ++rr) acc[rr] = bv;
        for (int d0 = 0; d0 < HH; d0 += 4) {
            const float w0  = W3[(size_t)(d0 + 0) * DD + j];
            const float w1  = W3[(size_t)(d0 + 1) * DD + j];
            const float w2  = W3[(size_t)(d0 + 2) * DD + j];
            const float w3v = W3[(size_t)(d0 + 3) * DD + j];
            #pragma unroll
            for (int rr = 0; rr < 8; ++rr) {
                float4 a = *reinterpret_cast<const float4*>(&h2[8 * tr2 + rr][d0]);
                acc[rr] += a.x * w0 + a.y * w1 + a.z * w2 + a.w * w3v;
            }
        }
        #pragma unroll
        for (int rr = 0; rr < 8; ++rr) {
            const size_t oidx = (size_t)(r0 + 8 * tr2 + rr) * DD + j;
            const float y = acc[rr];
            const ushort hh = f2bf(y);
            YH[oidx] = hh;
            YL[oidx] = f2bf(y - bf2f(hh));
        }
    }
}

// ---------------------------------------------------------------------------
// Transpose VALUE's hi/lo bf16 [b*2048+tok][64] -> [b][64 j][2048 tok]
// (K-major layout for the PV B-operand fragments).
// FIX (R8): stage the FULL 16-ushort slice per thread (two uint4), not 8 —
// half the LDS tile was previously uninitialized -> NaN in V^T.
// ---------------------------------------------------------------------------
__global__ __launch_bounds__(256, 2) void transpose_bf16(
    const ushort* __restrict__ H, const ushort* __restrict__ L,
    ushort* __restrict__ TH, ushort* __restrict__ TL)
{
    __shared__ __align__(16) ushort th[64][72];
    __shared__ __align__(16) ushort tl[64][72];
    const int t = threadIdx.x;
    const int b = blockIdx.y, tok0 = blockIdx.x * 64;
    {
        const int r = t >> 2, c = (t & 3) * 16;
        const size_t src = ((size_t)b * NTOK + tok0 + r) * DD + c;
        *reinterpret_cast<uint4*>(&th[r][c])     = *reinterpret_cast<const uint4*>(H + src);
        *reinterpret_cast<uint4*>(&th[r][c + 8]) = *reinterpret_cast<const uint4*>(H + src + 8);
        *reinterpret_cast<uint4*>(&tl[r][c])     = *reinterpret_cast<const uint4*>(L + src);
        *reinterpret_cast<uint4*>(&tl[r][c + 8]) = *reinterpret_cast<const uint4*>(L + src + 8);
    }
    __syncthreads();
    {
        const int j = t & 63, sl = (t >> 6) * 16;
        unsigned oh[8], ol[8];
        #pragma unroll
        for (int m = 0; m < 8; ++m) {
            oh[m] = (unsigned)th[sl + 2 * m][j] | ((unsigned)th[sl + 2 * m + 1][j] << 16);
            ol[m] = (unsigned)tl[sl + 2 * m][j] | ((unsigned)tl[sl + 2 * m + 1][j] << 16);
        }
        const size_t dst = ((size_t)b * DD + j) * NTOK + tok0 + sl;
        *reinterpret_cast<uint4*>(TH + dst)     = make_uint4(oh[0], oh[1], oh[2], oh[3]);
        *reinterpret_cast<uint4*>(TH + dst + 8) = make_uint4(oh[4], oh[5], oh[6], oh[7]);
        *reinterpret_cast<uint4*>(TL + dst)     = make_uint4(ol[0], ol[1], ol[2], ol[3]);
        *reinterpret_cast<uint4*>(TL + dst + 8) = make_uint4(ol[4], ol[5], ol[6], ol[7]);
    }
}

// ---------------------------------------------------------------------------
// Pass A (MFMA): per key-row i, online (m, 1/l) over query axis k.
// C = Wq(M=k) x Wk^T(N=i), split-bf16 3-term. Waves split k-space; fragments
// fetched directly from global (L2-resident). Writes m_g and RECIPROCAL l.
// ---------------------------------------------------------------------------
__global__ __launch_bounds__(256, 2) void attn_stats_mfma(
    const ushort* __restrict__ KH, const ushort* __restrict__ KL,
    const ushort* __restrict__ QHp, const ushort* __restrict__ QLp,
    float* __restrict__ m_g, float* __restrict__ l_g)
{
    __shared__ float cm[4][2][16];
    __shared__ float cl[4][2][16];
    const int t = threadIdx.x, w = t >> 6, ln = t & 63;
    const int il = ln & 15, g = ln >> 4;
    const int b = blockIdx.y, i0 = blockIdx.x * 32;

    // hoist Wk B-frags (block's 32 i-rows, 2 n-tiles x 2 d-halves)
    s8v BH[2][2], BL[2][2];
    #pragma unroll
    for (int nt = 0; nt < 2; ++nt) {
        const size_t r = ((size_t)b * NTOK + i0 + nt * 16 + il) * DD + g * 8;
        BH[nt][0] = *reinterpret_cast<const s8v*>(KH + r);
        BH[nt][1] = *reinterpret_cast<const s8v*>(KH + r + 32);
        BL[nt][0] = *reinterpret_cast<const s8v*>(KL + r);
        BL[nt][1] = *reinterpret_cast<const s8v*>(KL + r + 32);
    }
    float mm[2] = { -INFINITY, -INFINITY };
    float ll[2] = { 0.f, 0.f };

    for (int kt = w; kt < NTOK / 16; kt += 4) {
        const size_t ar = ((size_t)b * NTOK + kt * 16 + il) * DD + g * 8;
        const s8v Ah0 = *reinterpret_cast<const s8v*>(QHp + ar);
        const s8v Ah1 = *reinterpret_cast<const s8v*>(QHp + ar + 32);
        const s8v Al0 = *reinterpret_cast<const s8v*>(QLp + ar);
        const s8v Al1 = *reinterpret_cast<const s8v*>(QLp + ar + 32);
        #pragma unroll
        for (int nt = 0; nt < 2; ++nt) {
            f4v c = { 0.f, 0.f, 0.f, 0.f };
            c = MFMA(Ah0, BH[nt][0], c, 0, 0, 0);
            c = MFMA(Ah1, BH[nt][1], c, 0, 0, 0);
            c = MFMA(Al0, BH[nt][0], c, 0, 0, 0);
            c = MFMA(Al1, BH[nt][1], c, 0, 0, 0);
            c = MFMA(Ah0, BL[nt][0], c, 0, 0, 0);
            c = MFMA(Ah1, BL[nt][1], c, 0, 0, 0);
            // C[r]: dist[k = kt*16 + 4g + r][i = i0 + nt*16 + il]
            #pragma unroll
            for (int r = 0; r < 4; ++r) {
                const float v = c[r] * SCALE2;
                const float d = v - mm[nt];
                const float e = exp2f(-fabsf(d));
                if (d <= 0.f) ll[nt] += e;
                else { ll[nt] = ll[nt] * e + 1.f; mm[nt] = v; }
            }
        }
    }
    // merge over lane k-groups (xor 16, 32)
    #pragma unroll
    for (int nt = 0; nt < 2; ++nt) {
        float m1 = mm[nt], l1 = ll[nt];
        #pragma unroll
        for (int off = 16; off < 64; off <<= 1) {
            const float m2 = __shfl_xor(m1, off);
            const float l2 = __shfl_xor(l1, off);
            const float mn = fmaxf(m1, m2);
            l1 = l1 * exp2f(m1 - mn) + l2 * exp2f(m2 - mn);
            m1 = mn;
        }
        if (ln < 16) { cm[w][nt][il] = m1; cl[w][nt][il] = l1; }
    }
    __syncthreads();
    if (t < 32) {   // merge 4 waves (disjoint k-subsets), write m and 1/l
        float m1 = cm[0][t >> 4][t & 15], l1 = cl[0][t >> 4][t & 15];
        #pragma unroll
        for (int ww = 1; ww < 4; ++ww) {
            const float m2 = cm[ww][t >> 4][t & 15], l2 = cl[ww][t >> 4][t & 15];
            const float mn = fmaxf(m1, m2);
            l1 = l1 * exp2f(m1 - mn) + l2 * exp2f(m2 - mn);
            m1 = mn;
        }
        m_g[(size_t)b * NTOK + i0 + t] = m1;
        l_g[(size_t)b * NTOK + i0 + t] = 1.0f / l1;
    }
}

// ---------------------------------------------------------------------------
// Pass B (MFMA): context[k,j] = sum_i P[i,k] Wv[i,j], split-bf16 3-term for
// both QK^T and PV. Block owns 16 k; waves split i-tiles; P round-trips
// through per-wave-private LDS in the A-fragment layout. No main-loop barrier.
// ---------------------------------------------------------------------------
__global__ __launch_bounds__(256, 4) void attn_ctx_mfma(
    const ushort* __restrict__ KH, const ushort* __restrict__ KL,
    const ushort* __restrict__ QHp, const ushort* __restrict__ QLp,
    const ushort* __restrict__ VTH, const ushort* __restrict__ VTL,
    const float* __restrict__ m_g, const float* __restrict__ l_g,
    float* __restrict__ out)
{
    __shared__ __align__(16) ushort PtH[4][16][72];
    __shared__ __align__(16) ushort PtL[4][16][72];
    __shared__ __align__(16) float red[4][16][64];
    const int t = threadIdx.x, w = t >> 6, ln = t & 63;
    const int il = ln & 15, g = ln >> 4;
    const int b = blockIdx.y, k0 = blockIdx.x * 16;

    // hoist Wq B-frags (block's 16 queries)
    const size_t qr = ((size_t)b * NTOK + k0 + il) * DD + g * 8;
    const s8v Qh0 = *reinterpret_cast<const s8v*>(QHp + qr);
    const s8v Qh1 = *reinterpret_cast<const s8v*>(QHp + qr + 32);
    const s8v Ql0 = *reinterpret_cast<const s8v*>(QLp + qr);
    const s8v Ql1 = *reinterpret_cast<const s8v*>(QLp + qr + 32);

    f4v acc[4];
    #pragma unroll
    for (int nt = 0; nt < 4; ++nt) acc[nt] = (f4v){ 0.f, 0.f, 0.f, 0.f };

    for (int it = w; it < NTOK / 64; it += 4) {
        const int i0 = it * 64;
        // --- QK^T: C = Wk(M=i) x Wq^T(N=k) -> col = k = il, row = i ---
        #pragma unroll
        for (int mt = 0; mt < 4; ++mt) {
            const size_t kr = ((size_t)b * NTOK + i0 + mt * 16 + il) * DD + g * 8;
            const s8v Kh0 = *reinterpret_cast<const s8v*>(KH + kr);
            const s8v Kh1 = *reinterpret_cast<const s8v*>(KH + kr + 32);
            const s8v Kl0 = *reinterpret_cast<const s8v*>(KL + kr);
            const s8v Kl1 = *reinterpret_cast<const s8v*>(KL + kr + 32);
            f4v c = { 0.f, 0.f, 0.f, 0.f };
            c = MFMA(Kh0, Qh0, c, 0, 0, 0);
            c = MFMA(Kh1, Qh1, c, 0, 0, 0);
            c = MFMA(Kl0, Qh0, c, 0, 0, 0);
            c = MFMA(Kl1, Qh1, c, 0, 0, 0);
            c = MFMA(Kh0, Ql0, c, 0, 0, 0);
            c = MFMA(Kh1, Ql1, c, 0, 0, 0);
            // softmax: C[r] at (i = i0 + mt*16 + 4g + r, k = k0 + il)
            const int ib = i0 + mt * 16 + 4 * g;
            const f4v ms = *reinterpret_cast<const f4v*>(m_g + (size_t)b * NTOK + ib);
            const f4v rl = *reinterpret_cast<const f4v*>(l_g + (size_t)b * NTOK + ib);
            ushort ph[4], pl[4];
            #pragma unroll
            for (int r = 0; r < 4; ++r) {
                const float p = exp2f(c[r] * SCALE2 - ms[r]) * rl[r];
                ph[r] = f2bf(p);
                pl[r] = f2bf(p - bf2f(ph[r]));
            }
            const int col = mt * 16 + 4 * g;
            *reinterpret_cast<unsigned*>(&PtH[w][il][col])     = (unsigned)ph[0] | ((unsigned)ph[1] << 16);
            *reinterpret_cast<unsigned*>(&PtH[w][il][col + 2]) = (unsigned)ph[2] | ((unsigned)ph[3] << 16);
            *reinterpret_cast<unsigned*>(&PtL[w][il][col])     = (unsigned)pl[0] | ((unsigned)pl[1] << 16);
            *reinterpret_cast<unsigned*>(&PtL[w][il][col + 2]) = (unsigned)pl[2] | ((unsigned)pl[3] << 16);
        }
        __asm volatile("s_waitcnt lgkmcnt(0)" ::: "memory");
        __builtin_amdgcn_sched_barrier(0);
        // --- PV: A = P^T (16k x 64i from LDS), B = Wv_t (K-major from global) ---
        const s8v Ph0 = *reinterpret_cast<const s8v*>(&PtH[w][il][g * 8]);
        const s8v Ph1 = *reinterpret_cast<const s8v*>(&PtH[w][il][32 + g * 8]);
        const s8v Pl0 = *reinterpret_cast<const s8v*>(&PtL[w][il][g * 8]);
        const s8v Pl1 = *reinterpret_cast<const s8v*>(&PtL[w][il][32 + g * 8]);
        #pragma unroll
        for (int nt = 0; nt < 4; ++nt) {
            const size_t vr = ((size_t)b * DD + nt * 16 + il) * NTOK + i0 + g * 8;
            const s8v Vh0 = *reinterpret_cast<const s8v*>(VTH + vr);
            const s8v Vh1 = *reinterpret_cast<const s8v*>(VTH + vr + 32);
            const s8v Vl0 = *reinterpret_cast<const s8v*>(VTL + vr);
            const s8v Vl1 = *reinterpret_cast<const s8v*>(VTL + vr + 32);
            acc[nt] = MFMA(Ph0, Vh0, acc[nt], 0, 0, 0);
            acc[nt] = MFMA(Ph1, Vh1, acc[nt], 0, 0, 0);
            acc[nt] = MFMA(Pl0, Vh0, acc[nt], 0, 0, 0);
            acc[nt] = MFMA(Pl1, Vh1, acc[nt], 0, 0, 0);
            acc[nt] = MFMA(Ph0, Vl0, acc[nt], 0, 0, 0);
            acc[nt] = MFMA(Ph1, Vl1, acc[nt], 0, 0, 0);
        }
    }
    // reduce over the 4 waves' i-subsets
    #pragma unroll
    for (int nt = 0; nt < 4; ++nt) {
        #pragma unroll
        for (int r = 0; r < 4; ++r)
            red[w][4 * g + r][nt * 16 + il] = acc[nt][r];
    }
    __syncthreads();
    {
        const int kk = t >> 4, j = (t & 15) * 4;
        f4v s = *reinterpret_cast<const f4v*>(&red[0][kk][j]);
        #pragma unroll
        for (int ww = 1; ww < 4; ++ww) {
            const f4v s2 = *reinterpret_cast<const f4v*>(&red[ww][kk][j]);
            s[0] += s2[0]; s[1] += s2[1]; s[2] += s2[2]; s[3] += s2[3];
        }
        *reinterpret_cast<f4v*>(out + ((size_t)b * NTOK + k0 + kk) * DD + j) = s;
    }
}

// ---------------------------------------------------------------------------
extern "C" void kernel_launch(void* const* d_in, const int* in_sizes, int n_in,
                              void* d_out, int out_size, void* d_ws, size_t ws_size,
                              hipStream_t stream) {
    const float* KEY   = (const float*)d_in[0];
    const float* VALUE = (const float*)d_in[1];
    const float* QUERY = (const float*)d_in[2];
    const float* Wk1 = (const float*)d_in[3];
    const float* bk1 = (const float*)d_in[4];
    const float* Wk2 = (const float*)d_in[5];
    const float* bk2 = (const float*)d_in[6];
    const float* Wk3 = (const float*)d_in[7];
    const float* bk3 = (const float*)d_in[8];
    const float* Wv1 = (const float*)d_in[9];
    const float* bv1 = (const float*)d_in[10];
    const float* Wv2 = (const float*)d_in[11];
    const float* bv2 = (const float*)d_in[12];
    const float* Wv3 = (const float*)d_in[13];
    const float* bv3 = (const float*)d_in[14];

    // ws layout (12.13 MB total; VALUE's row-major buffers are reused for KEY
    // after the transpose — stream-ordered, safe):
    char* wsb = (char*)d_ws;
    ushort* AH  = (ushort*)(wsb);                         // 2MB: Wv_hi rm -> Wk_hi
    ushort* AL  = (ushort*)(wsb + (size_t)(2u  << 20));   // 2MB: Wv_lo rm -> Wk_lo
    ushort* VTH = (ushort*)(wsb + (size_t)(4u  << 20));   // 2MB: Wv_t hi
    ushort* VTL = (ushort*)(wsb + (size_t)(6u  << 20));   // 2MB: Wv_t lo
    ushort* QH_ = (ushort*)(wsb + (size_t)(8u  << 20));   // 2MB: Wq_hi
    ushort* QL_ = (ushort*)(wsb + (size_t)(10u << 20));   // 2MB: Wq_lo
    float*  m_g = (float*)(wsb + (size_t)(12u << 20));    // 64KB
    float*  l_g = (float*)(wsb + (size_t)(12u << 20) + (size_t)(64u << 10)); // 64KB (stores 1/l)

    mlp_kernel<<<NROWS / 32, 256, 0, stream>>>(VALUE, AH, AL, Wv1, bv1, Wv2, bv2, Wv3, bv3);
    transpose_bf16<<<dim3(NTOK / 64, NB), 256, 0, stream>>>(AH, AL, VTH, VTL);
    mlp_kernel<<<NROWS / 32, 256, 0, stream>>>(KEY,   AH, AL, Wk1, bk1, Wk2, bk2, Wk3, bk3);
    mlp_kernel<<<NROWS / 32, 256, 0, stream>>>(QUERY, QH_, QL_, Wk1, bk1, Wk2, bk2, Wk3, bk3);

    attn_stats_mfma<<<dim3(NTOK / 32, NB), 256, 0, stream>>>(AH, AL, QH_, QL_, m_g, l_g);
    attn_ctx_mfma<<<dim3(NTOK / 16, NB), 256, 0, stream>>>(AH, AL, QH_, QL_, VTH, VTL,
                                                           m_g, l_g, (float*)d_out);
}